// Round 8
// baseline (503.339 us; speedup 1.0000x reference)
//
#include <hip/hip_runtime.h>
#include <stdint.h>

// Problem constants (from reference)
#define HH 176
#define WW 200
#define BB 4
#define CIN 128
#define COUT 256
#define NPTS (4096 * 64)            // 262144 points
#define CELLS (BB * WW * HH)        // 140800 cells = 8800 * 16
#define FEAT_OUT_ELEMS ((size_t)NPTS * COUT)  // 67108864
#define CAP 32                      // max points/cell tracked (Poisson lambda~1.6 -> max ~12)
#define BCELLS 16                   // cells per BLOCK (one MFMA N-tile), 4 waves
#define LDSWN 132                   // normed ushort stride (measured conflict-clean)
#define LDSWO 260                   // out16 ushort stride (measured conflict-clean)

typedef __attribute__((ext_vector_type(8))) short bf16x8;
typedef __attribute__((ext_vector_type(4))) float f32x4;

// ---------- bf16 helpers (RNE) ----------
__device__ __forceinline__ unsigned short f2bf(float f) {
    union { float f; unsigned int u; } c; c.f = f;
    unsigned int u = c.u;
    u += 0x7fffu + ((u >> 16) & 1u);
    return (unsigned short)(u >> 16);
}
__device__ __forceinline__ float bf2f(unsigned int h16) {
    union { unsigned int u; float f; } c; c.u = h16 << 16;
    return c.f;
}

// ---------- 0. prep: zero counts + convert W to bf16 ----------
__global__ __launch_bounds__(256) void prep_kernel(
    const float* __restrict__ lw, unsigned short* __restrict__ wb,
    int* __restrict__ counts)
{
    int i = blockIdx.x * 256 + threadIdx.x;   // grid 550 -> i < 140800
    if (i < COUT * CIN) wb[i] = f2bf(lw[i]);
    counts[i] = 0;
}

// ---------- 1. build: per-cell point lists ONLY (echo/zeroing moved to writeout) ----------
__global__ __launch_bounds__(256) void build_kernel(
    const int* __restrict__ idx, int* __restrict__ counts, int* __restrict__ plist)
{
    int p = blockIdx.x * 256 + threadIdx.x;
    int b = idx[3 * p], x = idx[3 * p + 1], y = idx[3 * p + 2];
    if ((unsigned)x < HH && (unsigned)y < WW) {
        int cell = (b * WW + y) * HH + x;
        int slot = atomicAdd(&counts[cell], 1);
        if (slot < CAP) plist[(size_t)cell * CAP + slot] = p;
    }
}

// ---------- 2. cellgemm: accumulate + LN + MFMA -> Cd (SEQUENTIAL writes) ----------
// R7's fused structure (16 cells / 4 waves / 2 thin barriers) with the random
// scatter replaced by a coalesced 8 KB cell-ordered tile store. All HBM writes
// from this kernel are sequential; the random stream (feats rows) is read-only
// and largely L3-resident (134 MB < 256 MB Infinity Cache).
__global__ __launch_bounds__(256) void cellgemm_kernel(
    const float* __restrict__ feats,
    const unsigned short* __restrict__ Wb,   // [256][128] bf16
    const int* __restrict__ counts,
    const int* __restrict__ plist,
    const float* __restrict__ nw, const float* __restrict__ nb,
    unsigned short* __restrict__ Cd)         // [CELLS][256] bf16
{
    __shared__ unsigned short normedl[BCELLS * LDSWN];  // 4224 B
    __shared__ unsigned short out16[BCELLS * LDSWO];    // 8320 B

    int tid = threadIdx.x;
    int w = tid >> 6, lane = tid & 63;
    int l15 = lane & 15, g = lane >> 4;
    int kgrp = g * 8, orow = g * 4;
    int c0 = blockIdx.x * BCELLS;
    int cw0 = c0 + w * 4;                    // this wave's 4 cells

    float w0 = nw[lane * 2], w1 = nw[lane * 2 + 1];
    float b0 = nb[lane * 2], b1 = nb[lane * 2 + 1];

    // wave metadata: 4 counts + 4 pid-quads (independent loads)
    int cnts[4];
    int4 pq[4];
    #pragma unroll
    for (int ci = 0; ci < 4; ++ci) {
        int n = counts[cw0 + ci];
        cnts[ci] = n < CAP ? n : CAP;
        pq[ci] = *(const int4*)(plist + (size_t)(cw0 + ci) * CAP);
    }

    // ---- accumulate + LN per cell (loads independent across cells) ----
    #pragma unroll
    for (int ci = 0; ci < 4; ++ci) {
        int cnt = cnts[ci];
        float s0 = 0.0f, s1 = 0.0f;
        if (cnt > 0) { float2 t = *(const float2*)(feats + (size_t)pq[ci].x * CIN + lane * 2); s0 += t.x; s1 += t.y; }
        if (cnt > 1) { float2 t = *(const float2*)(feats + (size_t)pq[ci].y * CIN + lane * 2); s0 += t.x; s1 += t.y; }
        if (cnt > 2) { float2 t = *(const float2*)(feats + (size_t)pq[ci].z * CIN + lane * 2); s0 += t.x; s1 += t.y; }
        if (cnt > 3) { float2 t = *(const float2*)(feats + (size_t)pq[ci].w * CIN + lane * 2); s0 += t.x; s1 += t.y; }
        if (cnt > 4) {                       // rare (~2% of cells), wave-uniform
            for (int s = 4; s < cnt; ++s) {
                int pid = plist[(size_t)(cw0 + ci) * CAP + s];
                float2 t = *(const float2*)(feats + (size_t)pid * CIN + lane * 2);
                s0 += t.x; s1 += t.y;
            }
        }
        float s = s0 + s1, ss = s0 * s0 + s1 * s1;
        #pragma unroll
        for (int m = 32; m >= 1; m >>= 1) {
            s  += __shfl_xor(s, m, 64);
            ss += __shfl_xor(ss, m, 64);
        }
        float mu  = s * (1.0f / 128.0f);
        float var = ss * (1.0f / 128.0f) - mu * mu;
        float inv = rsqrtf(var + 1e-5f);
        ushort2 st;
        st.x = f2bf((s0 - mu) * inv * w0 + b0);
        st.y = f2bf((s1 - mu) * inv * w1 + b1);
        *(ushort2*)(&normedl[(w * 4 + ci) * LDSWN + lane * 2]) = st;
    }
    __syncthreads();   // #1: normedl ready

    // ---- MFMA: wave w owns o-band [64w, 64w+64) = 4 o-tiles ----
    bf16x8 bfr[4];
    #pragma unroll
    for (int kk = 0; kk < 4; ++kk)
        bfr[kk] = *(const bf16x8*)(&normedl[l15 * LDSWN + kgrp + kk * 32]);

    #pragma unroll
    for (int i = 0; i < 4; ++i) {
        f32x4 acc = (f32x4){0.0f, 0.0f, 0.0f, 0.0f};
        #pragma unroll
        for (int kk = 0; kk < 4; ++kk) {
            bf16x8 av = *(const bf16x8*)(Wb + (size_t)((w * 64 + i * 16 + l15) * CIN) + kgrp + kk * 32);
            acc = __builtin_amdgcn_mfma_f32_16x16x32_bf16(av, bfr[kk], acc, 0, 0, 0);
        }
        // C/D layout: col(cell)=l15, row(o)=g*4+reg -> transpose into out16
        ushort4 st;
        st.x = f2bf(acc[0]);
        st.y = f2bf(acc[1]);
        st.z = f2bf(acc[2]);
        st.w = f2bf(acc[3]);
        *(ushort4*)(&out16[l15 * LDSWO + w * 64 + i * 16 + orow]) = st;
    }
    __syncthreads();   // #2: out16 ready

    // ---- coalesced tile store: 16 cells x 256 ch bf16 = 8 KB contiguous ----
    #pragma unroll
    for (int r = 0; r < 4; ++r) {
        int e = r * 256 + tid;               // ushort4 index within tile
        int c = e >> 6;                      // 64 ushort4 per cell row
        int q = e & 63;
        *(ushort4*)(Cd + (size_t)(c0 + c) * COUT + q * 4) =
            *(const ushort4*)(&out16[c * LDSWO + q * 4]);
    }
}

// ---------- 3. writeout: point-ordered gather -> SEQUENTIAL out writes ----------
// Per wave: 2 points, both Cd row loads in flight before either out write.
// Cd (72 MB) is L3-resident -> random reads don't thrash HBM pages. All out
// writes (valid rows, zero rows, idx echo) are sequential streams.
__global__ __launch_bounds__(256) void writeout_kernel(
    const unsigned short* __restrict__ Cd, const int* __restrict__ idx,
    float* __restrict__ out_feats, float* __restrict__ out_idx)
{
    int tid = threadIdx.x;
    int w = tid >> 6, lane = tid & 63;
    int pbase = blockIdx.x * 8;              // 8 points per block

    // idx echo: 24 consecutive values per block, sequential
    if (tid < 24) out_idx[(size_t)pbase * 3 + tid] = (float)idx[pbase * 3 + tid];

    int pA = pbase + w * 2, pB = pA + 1;
    int bA = idx[3 * pA], xA = idx[3 * pA + 1], yA = idx[3 * pA + 2];
    int bB = idx[3 * pB], xB = idx[3 * pB + 1], yB = idx[3 * pB + 2];
    bool vA = ((unsigned)xA < HH && (unsigned)yA < WW);
    bool vB = ((unsigned)xB < HH && (unsigned)yB < WW);

    uint2 dA = {0u, 0u}, dB = {0u, 0u};
    if (vA) {
        size_t cA = ((size_t)bA * WW + yA) * HH + xA;
        dA = *(const uint2*)(Cd + cA * COUT + lane * 4);
    }
    if (vB) {
        size_t cB = ((size_t)bB * WW + yB) * HH + xB;
        dB = *(const uint2*)(Cd + cB * COUT + lane * 4);
    }

    float4 oA, oB;
    oA.x = bf2f(dA.x & 0xffffu); oA.y = bf2f(dA.x >> 16);
    oA.z = bf2f(dA.y & 0xffffu); oA.w = bf2f(dA.y >> 16);
    oB.x = bf2f(dB.x & 0xffffu); oB.y = bf2f(dB.x >> 16);
    oB.z = bf2f(dB.y & 0xffffu); oB.w = bf2f(dB.y >> 16);

    *(float4*)(out_feats + (size_t)pA * COUT + lane * 4) = oA;
    *(float4*)(out_feats + (size_t)pB * COUT + lane * 4) = oB;
}

extern "C" void kernel_launch(void* const* d_in, const int* in_sizes, int n_in,
                              void* d_out, int out_size, void* d_ws, size_t ws_size,
                              hipStream_t stream)
{
    const float* feats = (const float*)d_in[0];
    const int*   idx   = (const int*)d_in[1];
    const float* nw    = (const float*)d_in[2];
    const float* nb    = (const float*)d_in[3];
    const float* lw    = (const float*)d_in[4];
    float* out = (float*)d_out;

    char* ws = (char*)d_ws;
    int* counts = (int*)ws;                                        // 0.56 MB
    int* plist  = (int*)(ws + (1u << 20));                         // 18 MB
    unsigned short* wb = (unsigned short*)(ws + (20u << 20));      // 64 KB bf16
    unsigned short* Cd = (unsigned short*)(ws + (21u << 20));      // 72.1 MB bf16

    prep_kernel<<<CELLS / 256, 256, 0, stream>>>(lw, wb, counts);
    build_kernel<<<NPTS / 256, 256, 0, stream>>>(idx, counts, plist);
    cellgemm_kernel<<<CELLS / BCELLS, 256, 0, stream>>>(feats, wb, counts, plist, nw, nb, Cd);
    writeout_kernel<<<NPTS / 8, 256, 0, stream>>>(Cd, idx, out, out + FEAT_OUT_ELEMS);
}